// Round 9
// baseline (66.188 us; speedup 1.0000x reference)
//
#include <hip/hip_runtime.h>
#include <hip/hip_bf16.h>
#include <math.h>

// PNA layer, R9: bf16 MFMA; barrier-free gather start (nbr_idx read direct from
// global), explicit 2-deep software pipeline over the 4 pretrans tiles,
// hoisted post-weight loads, half-wave-split stats stores.
//   u = h@W1 + b_pre (bf16, precomputed)   W1 = W_pre rows 0:64
//   v = h@W2         (bf16, precomputed)   W2 = W_pre rows 64:128
//   per 16-node block (256 edges):
//     per 32-edge x 32-col tile: acc = mfma32x32x16(ea_bf16, W3, 0)
//     e = relu(acc + u[nbr] + v);  agg = [mean,max,min,std] over d
//     y1 = relu([h,agg]@Wfull + b_post1)   Wfull = scaler-folded [320][64]
//     out = y1@W_post2 + b_post2 + h
// MFMA layouts:
//   16x16x32 (m89-verified): A row=lane&15,k=(lane>>4)*8+j; B col=lane&15 same k;
//                            C col=lane&15,row=(lane>>4)*4+reg
//   32x32x16 (C/D m74/m101-verified): A row=lane&31,k=(lane>>5)*8+j;
//                            B col=lane&31,k=(lane>>5)*8+j;
//                            C col=lane&31,row=(reg&3)+8*(reg>>2)+4*(lane>>5)

#define N_NODES 65536
#define NBLK (N_NODES / 16)       // 4096 main/uv blocks
#define GRID_PREP (NBLK + 64)     // + 64 weight-transpose blocks
#define ASTRIDE 348   // A_lds row stride (u16)
#define YSTRIDE 76    // y1_lds row stride (u16)

typedef float f32x4 __attribute__((ext_vector_type(4)));
typedef float f32x16 __attribute__((ext_vector_type(16)));
typedef short s16x8 __attribute__((ext_vector_type(8)));
typedef unsigned short us4 __attribute__((ext_vector_type(4)));
typedef int i32x4 __attribute__((ext_vector_type(4)));

__device__ __forceinline__ unsigned short f2bf(float f) {     // manual RNE
    union { float f; unsigned int u; } v; v.f = f;
    unsigned int r = v.u + 0x7fffu + ((v.u >> 16) & 1u);
    return (unsigned short)(r >> 16);
}
__device__ __forceinline__ unsigned short f2bfh(float f) {    // compiler cvt
    __hip_bfloat16 b = __float2bfloat16(f);
    union { __hip_bfloat16 b; unsigned short u; } v; v.b = b; return v.u;
}
__device__ __forceinline__ float bf2f(unsigned short u) {
    union { unsigned int u; float f; } v; v.u = ((unsigned int)u) << 16; return v.f;
}

// ---------------- prep: u/v via MFMA (blocks < NBLK) + weight transpose ----------------
__global__ __launch_bounds__(256) void k_prep(const float* __restrict__ h,
                                              const float* __restrict__ Wpre,
                                              const float* __restrict__ b_pre,
                                              const float* __restrict__ Wp1,
                                              const float* __restrict__ Wp2,
                                              unsigned short* __restrict__ u,
                                              unsigned short* __restrict__ vbf,
                                              unsigned short* __restrict__ wfullT,
                                              unsigned short* __restrict__ w3T,
                                              unsigned short* __restrict__ wp2T,
                                              float c1, float c2) {
    int t = threadIdx.x;
    if (blockIdx.x >= NBLK) {
        int c = blockIdx.x - NBLK;     // output col 0..63
        for (int k = t; k < 320; k += 256) {
            float v;
            if (k < 64) v = Wp1[k * 64 + c];
            else {
                int kk = k - 64;
                v = Wp1[(64 + kk) * 64 + c] + c1 * Wp1[(320 + kk) * 64 + c]
                                            + c2 * Wp1[(576 + kk) * 64 + c];
            }
            wfullT[c * 320 + k] = f2bf(v);
        }
        if (t < 16)              w3T[c * 16 + t]         = f2bf(Wpre[(128 + t) * 64 + c]);
        if (t >= 64 && t < 128)  wp2T[c * 64 + (t - 64)] = f2bf(Wp2[(t - 64) * 64 + c]);
        return;
    }

    // ---- uv blocks: [u|v] = h @ [W1|W2], 16 nodes, 4 waves x 32 cols ----
    __shared__ unsigned short hl[16 * 68];
    int lane = t & 63;
    int wv = __builtin_amdgcn_readfirstlane(t) >> 6;   // wave id (uniform)
    int c = lane & 15, g = lane >> 4;
    int node0 = blockIdx.x * 16;
    {
        int r = t >> 4, q = t & 15;
        float4 hv = *((const float4*)(h + (size_t)node0 * 64) + t);
        us4 o;
        o.x = f2bfh(hv.x); o.y = f2bfh(hv.y); o.z = f2bfh(hv.z); o.w = f2bfh(hv.w);
        *(us4*)&hl[r * 68 + q * 4] = o;
    }
    s16x8 bf[2][2];
    int woff = (wv < 2) ? 0 : 64;
    #pragma unroll
    for (int i2 = 0; i2 < 2; ++i2) {
        int wcol = ((wv & 1) * 32) + i2 * 16 + c;
        #pragma unroll
        for (int ks = 0; ks < 2; ++ks) {
            #pragma unroll
            for (int j = 0; j < 8; ++j)
                bf[i2][ks][j] = (short)f2bfh(Wpre[(woff + ks * 32 + g * 8 + j) * 64 + wcol]);
        }
    }
    __syncthreads();
    f32x4 acc0 = {0.f, 0.f, 0.f, 0.f}, acc1 = {0.f, 0.f, 0.f, 0.f};
    #pragma unroll
    for (int ks = 0; ks < 2; ++ks) {
        s16x8 a = *(const s16x8*)&hl[c * 68 + ks * 32 + g * 8];
        acc0 = __builtin_amdgcn_mfma_f32_16x16x32_bf16(a, bf[0][ks], acc0, 0, 0, 0);
        acc1 = __builtin_amdgcn_mfma_f32_16x16x32_bf16(a, bf[1][ks], acc1, 0, 0, 0);
    }
    unsigned short* dst = (wv < 2) ? u : vbf;
    #pragma unroll
    for (int i2 = 0; i2 < 2; ++i2) {
        int dcol = ((wv & 1) * 32) + i2 * 16 + c;
        float bp = (wv < 2) ? b_pre[dcol] : 0.f;
        const f32x4& av = i2 ? acc1 : acc0;
        #pragma unroll
        for (int i = 0; i < 4; ++i) {
            int row = g * 4 + i;
            dst[(size_t)(node0 + row) * 64 + dcol] = f2bfh(av[i] + bp);
        }
    }
}

// ---------------- fused main: one 16-node group per block ----------------
__global__ __launch_bounds__(256, 4) void k_main(
    const float* __restrict__ h,
    const float* __restrict__ edge_attr,
    const int* __restrict__ nbr_idx,
    const float* __restrict__ b_post1,
    const float* __restrict__ b_post2,
    const unsigned short* __restrict__ u,       // [N][64] bf16
    const unsigned short* __restrict__ vbf,     // [N][64] bf16
    const unsigned short* __restrict__ wfullT,  // [64][320] bf16 (L2-resident)
    const unsigned short* __restrict__ w3T,     // [64][16]
    const unsigned short* __restrict__ wp2T,    // [64][64]
    float* __restrict__ out) {
    __shared__ unsigned short A_lds[16 * ASTRIDE];   // 11136 B
    __shared__ unsigned short y1_lds[16 * YSTRIDE];  // 2432 B

    int t = threadIdx.x;
    int lane = t & 63;
    int wu2 = __builtin_amdgcn_readfirstlane(t) >> 6;   // wave id (uniform)
    int c = lane & 15;          // 16x16 frag col / A-row
    int g = lane >> 4;          // 16x16 k-group
    int l32 = lane & 31;        // 32x32 frag row/col
    int h2 = lane >> 5;         // 32x32 k-half
    int ct = wu2 & 1;           // 32-col tile (uniform)
    int wr = wu2 >> 1;          // row-tile base (uniform)
    int colb = ct * 32 + l32;   // pretrans output col
    int cb2 = colb * 2;         // byte offset within a 128B u/v row
    int col16 = wu2 * 16 + c;   // post1/post2 output col
    int node0 = blockIdx.x * 16;

    s16x8 w3b = *(const s16x8*)&w3T[colb * 16 + h2 * 8];
    float b1c = b_post1[col16];
    float b2c = b_post2[col16];

    const char* ub = (const char*)u;
    const char* vb = (const char*)vbf + ((unsigned)node0 << 7) + (unsigned)(wr * 256) + cb2;
    const char* eb = (const char*)edge_attr
                   + ((size_t)node0 * 16 + wr * 32 + l32) * 64 + h2 * 32;

    // ---- stage h (bf16) into A_lds; fenced by the post-pretrans barrier ----
    {
        int r = t >> 4, q = t & 15;
        float4 hv = *((const float4*)(h + (size_t)node0 * 64) + t);
        us4 o;
        o.x = f2bfh(hv.x); o.y = f2bfh(hv.y); o.z = f2bfh(hv.z); o.w = f2bfh(hv.w);
        *(us4*)&A_lds[r * ASTRIDE + q * 4] = o;
    }

    // ---- pretrans: 4 tiles, explicit 2-deep software pipeline ----
#define ISSUE(S, IT)                                                           \
    const int* nb##S = nbr_idx + node0 * 16 + (wr + 2 * (IT)) * 32 + 4 * h2;   \
    i32x4 ja##S = *(const i32x4*)(nb##S);                                      \
    i32x4 jb##S = *(const i32x4*)(nb##S + 8);                                  \
    i32x4 jc##S = *(const i32x4*)(nb##S + 16);                                 \
    i32x4 jd##S = *(const i32x4*)(nb##S + 24);                                 \
    float4 xa##S = *(const float4*)(eb + (IT) * 4096);                         \
    float4 xb##S = *(const float4*)(eb + (IT) * 4096 + 16);                    \
    unsigned short g0##S  = *(const unsigned short*)(ub + (unsigned)((ja##S[0] << 7) + cb2)); \
    unsigned short g1##S  = *(const unsigned short*)(ub + (unsigned)((ja##S[1] << 7) + cb2)); \
    unsigned short g2##S  = *(const unsigned short*)(ub + (unsigned)((ja##S[2] << 7) + cb2)); \
    unsigned short g3##S  = *(const unsigned short*)(ub + (unsigned)((ja##S[3] << 7) + cb2)); \
    unsigned short g4##S  = *(const unsigned short*)(ub + (unsigned)((jb##S[0] << 7) + cb2)); \
    unsigned short g5##S  = *(const unsigned short*)(ub + (unsigned)((jb##S[1] << 7) + cb2)); \
    unsigned short g6##S  = *(const unsigned short*)(ub + (unsigned)((jb##S[2] << 7) + cb2)); \
    unsigned short g7##S  = *(const unsigned short*)(ub + (unsigned)((jb##S[3] << 7) + cb2)); \
    unsigned short g8##S  = *(const unsigned short*)(ub + (unsigned)((jc##S[0] << 7) + cb2)); \
    unsigned short g9##S  = *(const unsigned short*)(ub + (unsigned)((jc##S[1] << 7) + cb2)); \
    unsigned short g10##S = *(const unsigned short*)(ub + (unsigned)((jc##S[2] << 7) + cb2)); \
    unsigned short g11##S = *(const unsigned short*)(ub + (unsigned)((jc##S[3] << 7) + cb2)); \
    unsigned short g12##S = *(const unsigned short*)(ub + (unsigned)((jd##S[0] << 7) + cb2)); \
    unsigned short g13##S = *(const unsigned short*)(ub + (unsigned)((jd##S[1] << 7) + cb2)); \
    unsigned short g14##S = *(const unsigned short*)(ub + (unsigned)((jd##S[2] << 7) + cb2)); \
    unsigned short g15##S = *(const unsigned short*)(ub + (unsigned)((jd##S[3] << 7) + cb2)); \
    unsigned short va##S = *(const unsigned short*)(vb + (IT) * 512);          \
    unsigned short vc##S = *(const unsigned short*)(vb + (IT) * 512 + 128);

#define COMPUTE(S, IT) {                                                       \
    s16x8 a;                                                                   \
    a[0] = (short)f2bfh(xa##S.x); a[1] = (short)f2bfh(xa##S.y);                \
    a[2] = (short)f2bfh(xa##S.z); a[3] = (short)f2bfh(xa##S.w);                \
    a[4] = (short)f2bfh(xb##S.x); a[5] = (short)f2bfh(xb##S.y);                \
    a[6] = (short)f2bfh(xb##S.z); a[7] = (short)f2bfh(xb##S.w);                \
    f32x16 acc = {};                                                           \
    acc = __builtin_amdgcn_mfma_f32_32x32x16_bf16(a, w3b, acc, 0, 0, 0);       \
    float v0 = bf2f(va##S), v1 = bf2f(vc##S);                                  \
    float e0  = fmaxf(acc[0]  + bf2f(g0##S)  + v0, 0.f);                       \
    float e1  = fmaxf(acc[1]  + bf2f(g1##S)  + v0, 0.f);                       \
    float e2  = fmaxf(acc[2]  + bf2f(g2##S)  + v0, 0.f);                       \
    float e3  = fmaxf(acc[3]  + bf2f(g3##S)  + v0, 0.f);                       \
    float e4  = fmaxf(acc[4]  + bf2f(g4##S)  + v0, 0.f);                       \
    float e5  = fmaxf(acc[5]  + bf2f(g5##S)  + v0, 0.f);                       \
    float e6  = fmaxf(acc[6]  + bf2f(g6##S)  + v0, 0.f);                       \
    float e7  = fmaxf(acc[7]  + bf2f(g7##S)  + v0, 0.f);                       \
    float e8  = fmaxf(acc[8]  + bf2f(g8##S)  + v1, 0.f);                       \
    float e9  = fmaxf(acc[9]  + bf2f(g9##S)  + v1, 0.f);                       \
    float e10 = fmaxf(acc[10] + bf2f(g10##S) + v1, 0.f);                       \
    float e11 = fmaxf(acc[11] + bf2f(g11##S) + v1, 0.f);                       \
    float e12 = fmaxf(acc[12] + bf2f(g12##S) + v1, 0.f);                       \
    float e13 = fmaxf(acc[13] + bf2f(g13##S) + v1, 0.f);                       \
    float e14 = fmaxf(acc[14] + bf2f(g14##S) + v1, 0.f);                       \
    float e15 = fmaxf(acc[15] + bf2f(g15##S) + v1, 0.f);                       \
    float s1a = ((e0 + e1) + (e2 + e3)) + ((e4 + e5) + (e6 + e7));             \
    float s2a = fmaf(e0, e0, fmaf(e1, e1, fmaf(e2, e2, e3 * e3)))              \
              + fmaf(e4, e4, fmaf(e5, e5, fmaf(e6, e6, e7 * e7)));             \
    float mxa = fmaxf(fmaxf(fmaxf(e0, e1), fmaxf(e2, e3)),                     \
                      fmaxf(fmaxf(e4, e5), fmaxf(e6, e7)));                    \
    float mna = fminf(fminf(fminf(e0, e1), fminf(e2, e3)),                     \
                      fminf(fminf(e4, e5), fminf(e6, e7)));                    \
    float s1b = ((e8 + e9) + (e10 + e11)) + ((e12 + e13) + (e14 + e15));       \
    float s2b = fmaf(e8, e8, fmaf(e9, e9, fmaf(e10, e10, e11 * e11)))          \
              + fmaf(e12, e12, fmaf(e13, e13, fmaf(e14, e14, e15 * e15)));     \
    float mxb = fmaxf(fmaxf(fmaxf(e8, e9), fmaxf(e10, e11)),                   \
                      fmaxf(fmaxf(e12, e13), fmaxf(e14, e15)));                \
    float mnb = fminf(fminf(fminf(e8, e9), fminf(e10, e11)),                   \
                      fminf(fminf(e12, e13), fminf(e14, e15)));                \
    s1a += __shfl_xor(s1a, 32); s2a += __shfl_xor(s2a, 32);                    \
    mxa = fmaxf(mxa, __shfl_xor(mxa, 32)); mna = fminf(mna, __shfl_xor(mna, 32)); \
    s1b += __shfl_xor(s1b, 32); s2b += __shfl_xor(s2b, 32);                    \
    mxb = fmaxf(mxb, __shfl_xor(mxb, 32)); mnb = fminf(mnb, __shfl_xor(mnb, 32)); \
    float S1 = h2 ? s1b : s1a;                                                 \
    float S2 = h2 ? s2b : s2a;                                                 \
    float MX = h2 ? mxb : mxa;                                                 \
    float MN = h2 ? mnb : mna;                                                 \
    float M  = S1 * 0.0625f;                                                   \
    float SD = sqrtf(fmaxf(fmaf(-M, M, S2 * 0.0625f), 0.f) + 1e-5f);           \
    unsigned short* pd = &A_lds[(2 * (wr + 2 * (IT)) + h2) * ASTRIDE + 64 + colb]; \
    pd[0]   = f2bfh(M);                                                        \
    pd[64]  = f2bfh(MX);                                                       \
    pd[128] = f2bfh(MN);                                                       \
    pd[192] = f2bfh(SD);                                                       \
}

    ISSUE(T0, 0)
    ISSUE(T1, 1)
    COMPUTE(T0, 0)
    ISSUE(T2, 2)
    COMPUTE(T1, 1)
    ISSUE(T3, 3)
    COMPUTE(T2, 2)
    COMPUTE(T3, 3)
#undef ISSUE
#undef COMPUTE

    // ---- hoist post1 weight loads (latency hides under barrier wait) ----
    s16x8 wf[10];
    #pragma unroll
    for (int ks = 0; ks < 10; ++ks)
        wf[ks] = *(const s16x8*)&wfullT[col16 * 320 + ks * 32 + g * 8];
    __syncthreads();

    // ---- post1: y1 = relu([h,agg]@Wfull + b1), K=320 ----
    {
        f32x4 y1 = {0.f, 0.f, 0.f, 0.f};
        #pragma unroll
        for (int ks = 0; ks < 10; ++ks) {
            s16x8 a = *(const s16x8*)&A_lds[c * ASTRIDE + ks * 32 + g * 8];
            y1 = __builtin_amdgcn_mfma_f32_16x16x32_bf16(a, wf[ks], y1, 0, 0, 0);
        }
        #pragma unroll
        for (int i = 0; i < 4; ++i)
            y1_lds[(g * 4 + i) * YSTRIDE + col16] = f2bfh(fmaxf(y1[i] + b1c, 0.f));
    }

    // ---- hoist post2 weight loads ----
    s16x8 wp0 = *(const s16x8*)&wp2T[col16 * 64 + 0 * 32 + g * 8];
    s16x8 wp1 = *(const s16x8*)&wp2T[col16 * 64 + 1 * 32 + g * 8];
    __syncthreads();

    // ---- post2 + residual (h re-read from global; L1-warm) ----
    {
        f32x4 o = {0.f, 0.f, 0.f, 0.f};
        {
            s16x8 a0 = *(const s16x8*)&y1_lds[c * YSTRIDE + 0 * 32 + g * 8];
            s16x8 a1 = *(const s16x8*)&y1_lds[c * YSTRIDE + 1 * 32 + g * 8];
            o = __builtin_amdgcn_mfma_f32_16x16x32_bf16(a0, wp0, o, 0, 0, 0);
            o = __builtin_amdgcn_mfma_f32_16x16x32_bf16(a1, wp1, o, 0, 0, 0);
        }
        #pragma unroll
        for (int i = 0; i < 4; ++i) {
            int r = g * 4 + i;
            out[(size_t)(node0 + r) * 64 + col16] =
                o[i] + b2c + h[(size_t)(node0 + r) * 64 + col16];
        }
    }
}

extern "C" void kernel_launch(void* const* d_in, const int* in_sizes, int n_in,
                              void* d_out, int out_size, void* d_ws, size_t ws_size,
                              hipStream_t stream) {
    const float* h         = (const float*)d_in[0];
    const float* edge_attr = (const float*)d_in[1];
    const int*   nbr_idx   = (const int*)d_in[2];
    const float* W_pre     = (const float*)d_in[3];
    const float* b_pre     = (const float*)d_in[4];
    const float* W_post1   = (const float*)d_in[5];
    const float* b_post1   = (const float*)d_in[6];
    const float* W_post2   = (const float*)d_in[7];
    const float* b_post2   = (const float*)d_in[8];
    float* out = (float*)d_out;

    size_t need = (size_t)N_NODES * 64 * 2 * 2 + (64 * 320 + 64 * 16 + 64 * 64) * 2;
    if (ws_size < need) return;   // ~16.05 MiB
    unsigned short* u      = (unsigned short*)d_ws;       // [N][64] bf16
    unsigned short* vbf    = u + (size_t)N_NODES * 64;    // [N][64] bf16
    unsigned short* wfullT = vbf + (size_t)N_NODES * 64;  // [64][320]
    unsigned short* w3T    = wfullT + 64 * 320;           // [64][16]
    unsigned short* wp2T   = w3T + 64 * 16;               // [64][64]

    double ld = log(16.0 + 1.0);                          // log(D+1)
    const double AVG = 2.302585092994046;
    float c1 = (float)(ld / AVG);
    float c2 = (float)(AVG / ld);

    k_prep<<<GRID_PREP, 256, 0, stream>>>(h, W_pre, b_pre, W_post1, W_post2,
                                          u, vbf, wfullT, w3T, wp2T, c1, c2);
    k_main<<<NBLK, 256, 0, stream>>>(h, edge_attr, nbr_idx, b_post1, b_post2,
                                     u, vbf, wfullT, w3T, wp2T, out);
}